// Round 2
// baseline (41.376 us; speedup 1.0000x reference)
//
#include <hip/hip_runtime.h>

// Masked MSE with ragged alignment — wave-per-row, barrier-free.
// Lane l owns elements [l*8, l*8+8) of each 512-element span. One wave64
// inclusive scan per span gives each masked element its rank within the row;
// gather target[row, rank], accumulate squared diff. No LDS, no syncthreads.
__global__ __launch_bounds__(256) void masked_mse_rows(
    const float* __restrict__ pred,
    const float* __restrict__ target,
    const int*   __restrict__ mask,
    float*       __restrict__ row_sums,
    int S, int B)
{
    const int tid  = threadIdx.x;
    const int lane = tid & 63;
    const int wid  = tid >> 6;
    const int row  = blockIdx.x * 4 + wid;
    if (row >= B) return;

    const float4* __restrict__ p4 = reinterpret_cast<const float4*>(pred + (size_t)row * S);
    const int4*   __restrict__ m4 = reinterpret_cast<const int4*>(mask + (size_t)row * S);
    const float*  __restrict__ trow = target + (size_t)row * S;

    float acc = 0.0f;
    int running = 0;                 // masked count so far in this row
    const int niter = S >> 9;        // 512 elements per wave-iteration

    #pragma unroll 2
    for (int it = 0; it < niter; ++it) {
        const int base = it * 128 + lane * 2;   // float4/int4 index
        const int4   ma = m4[base];
        const int4   mb = m4[base + 1];
        const float4 pa = p4[base];
        const float4 pb = p4[base + 1];

        const int b0 = (ma.x != 0), b1 = (ma.y != 0), b2 = (ma.z != 0), b3 = (ma.w != 0);
        const int b4 = (mb.x != 0), b5 = (mb.y != 0), b6 = (mb.z != 0), b7 = (mb.w != 0);
        const int cnt = b0 + b1 + b2 + b3 + b4 + b5 + b6 + b7;

        // wave64 inclusive scan of cnt
        int scan = cnt;
        #pragma unroll
        for (int off = 1; off < 64; off <<= 1) {
            int n = __shfl_up(scan, off, 64);
            if (lane >= off) scan += n;
        }

        int r = running + (scan - cnt);          // exclusive rank of lane's elem 0

        if (b0) { float d = pa.x - trow[r]; acc += d * d; ++r; }
        if (b1) { float d = pa.y - trow[r]; acc += d * d; ++r; }
        if (b2) { float d = pa.z - trow[r]; acc += d * d; ++r; }
        if (b3) { float d = pa.w - trow[r]; acc += d * d; ++r; }
        if (b4) { float d = pb.x - trow[r]; acc += d * d; ++r; }
        if (b5) { float d = pb.y - trow[r]; acc += d * d; ++r; }
        if (b6) { float d = pb.z - trow[r]; acc += d * d; ++r; }
        if (b7) { float d = pb.w - trow[r]; acc += d * d; ++r; }

        running += __shfl(scan, 63, 64);         // wave total, broadcast
    }

    // wave reduction of acc; lane 0 writes the row partial
    #pragma unroll
    for (int off = 32; off > 0; off >>= 1) acc += __shfl_down(acc, off, 64);
    if (lane == 0) row_sums[row] = acc;
}

// Deterministic final reduce of B row partials into d_out[0].
__global__ __launch_bounds__(256) void reduce_rows(
    const float* __restrict__ row_sums, float* __restrict__ out, int n)
{
    const int tid = threadIdx.x;
    float acc = 0.0f;
    for (int i = tid; i < n; i += 256) acc += row_sums[i];
    #pragma unroll
    for (int off = 32; off > 0; off >>= 1) acc += __shfl_down(acc, off, 64);
    __shared__ float facc[4];
    if ((tid & 63) == 0) facc[tid >> 6] = acc;
    __syncthreads();
    if (tid == 0) out[0] = facc[0] + facc[1] + facc[2] + facc[3];
}

extern "C" void kernel_launch(void* const* d_in, const int* in_sizes, int n_in,
                              void* d_out, int out_size, void* d_ws, size_t ws_size,
                              hipStream_t stream) {
    const float* pred   = (const float*)d_in[0];
    const float* target = (const float*)d_in[1];
    const int*   mask   = (const int*)d_in[2];
    float* out = (float*)d_out;
    float* row_sums = (float*)d_ws;

    const int S = 4096;
    const int B = in_sizes[0] / S;

    masked_mse_rows<<<(B + 3) / 4, 256, 0, stream>>>(pred, target, mask, row_sums, S, B);
    reduce_rows<<<1, 256, 0, stream>>>(row_sums, out, B);
}